// Round 21
// baseline (2349.928 us; speedup 1.0000x reference)
//
#include <hip/hip_runtime.h>
#include <math.h>

#define NN 4000
#define KC 384      // OpenBLAS SGEMM_DEFAULT_Q — fold granularity (bit-frozen)
#define LEAKY 0.25f
#define HBLK 1000   // histogram blocks (passes 2-4)
#define NPART1 2016 // tri64 blocks = partial rows for pass 1

// ===========================================================================
// Bit-frozen arithmetic (verified R6-R20, absmax must remain 0.001953125):
//   - per-output dot: blk = fmaf(a_k,b_k,blk) strict ascending k within each
//     KC=384 block; first block's total COPIED to acc, later blocks
//     acc = __fadd_rn(acc, blk) in order (OpenBLAS store-then-add).
//   - reductions: numpy pairwise_sum tree; elementwise: *_rn intrinsics.
// R21: double-buffered LDS staging in tri64 + gemm_s (load t+1 to regs ->
// compute t -> write regs to alt buffer -> ONE barrier/iter). Bit-exact:
// FMA chain & KC folds untouched; only staging overlap changes. LDS 25.6KB,
// still 4 blocks/CU (R19: the locality-balanced point).
// ===========================================================================

template<int EPI>
__device__ inline float epi_apply(float v, int r, int c,
                                  const float* __restrict__ bias,
                                  const float* __restrict__ wn)
{
    if (EPI == 1) {
        float s = __fadd_rn(v, bias[c]);
        return (s >= 0.f) ? s : __fmul_rn(LEAKY, s);
    }
    if (EPI == 2) {
        float den = fmaxf(__fmul_rn(wn[r], wn[c]), 1e-8f);
        return __fsub_rn(1.0f, __fdiv_rn(v, den));
    }
    return v;
}

// ---------------------------------------------------------------------------
// numpy pairwise_sum exact replica. XF=0: fl(v*v); XF=1: |v|.
// ---------------------------------------------------------------------------
template<int XF>
__device__ float xf(float v)
{
    if (XF == 0) return __fmul_rn(v, v);
    return fabsf(v);
}

template<int XF>
__device__ float np_pairwise(const float* a, int n)
{
    if (n < 8) {
        float r = 0.f;
        for (int i = 0; i < n; ++i) r = __fadd_rn(r, xf<XF>(a[i]));
        return r;
    }
    if (n <= 128) {
        float r[8];
#pragma unroll
        for (int j = 0; j < 8; ++j) r[j] = xf<XF>(a[j]);
        int i = 8;
        const int lim = n - (n & 7);
        for (; i < lim; i += 8)
#pragma unroll
            for (int j = 0; j < 8; ++j) r[j] = __fadd_rn(r[j], xf<XF>(a[i + j]));
        float res = __fadd_rn(__fadd_rn(__fadd_rn(r[0], r[1]), __fadd_rn(r[2], r[3])),
                              __fadd_rn(__fadd_rn(r[4], r[5]), __fadd_rn(r[6], r[7])));
        for (; i < n; ++i) res = __fadd_rn(res, xf<XF>(a[i]));
        return res;
    }
    int n2 = (n / 2) & ~7;
    return __fadd_rn(np_pairwise<XF>(a, n2), np_pairwise<XF>(a + n2, n - n2));
}

// ---------------------------------------------------------------------------
// Double-buffered fused-KC 64x64 triangular dist GEMM (EPI=2), tiles bi<=bj.
// 4x4/thread, float4 stores. Epilogue: radix pass-1 weighted histogram.
// ---------------------------------------------------------------------------
__global__ __launch_bounds__(256, 4)
void gemm_tri64_k(const float* __restrict__ A, float* __restrict__ C,
                  unsigned* __restrict__ partial, int n, int K,
                  const float* __restrict__ wn)
{
    __shared__ float As[2][16][68];
    __shared__ float Bs[2][16][68];
    __shared__ unsigned lh[2048];   // 256 bins x 8 copies (pass-1 hist)
    const int tid = threadIdx.x;
    const int tx = tid & 15, ty = tid >> 4;
    const int sub = tid & 7;
    const int nt = (n + 63) >> 6;
    int bi = 0, rem = blockIdx.x;
    while (rem >= nt - bi) { rem -= nt - bi; ++bi; }
    const int bm = bi * 64, bn = (bi + rem) * 64;
    const bool diag = (rem == 0);

    for (int i = tid; i < 2048; i += 256) lh[i] = 0;

    const int srow = tid >> 2, sq = tid & 3;

    auto load_tile = [&](int k0, float4& ra, float4& rb) {
        int gk = k0 + sq * 4;
        ra = make_float4(0.f, 0.f, 0.f, 0.f);
        rb = make_float4(0.f, 0.f, 0.f, 0.f);
        int gr = bm + srow;
        if (gr < n) {
            if (gk + 3 < K) {
                ra = *(const float4*)(A + (size_t)gr * K + gk);
            } else {
                float* vp = (float*)&ra;
#pragma unroll
                for (int e = 0; e < 4; ++e)
                    if (gk + e < K) vp[e] = A[(size_t)gr * K + gk + e];
            }
        }
        int gc = bn + srow;
        if (gc < n) {
            if (gk + 3 < K) {
                rb = *(const float4*)(A + (size_t)gc * K + gk);
            } else {
                float* vp = (float*)&rb;
#pragma unroll
                for (int e = 0; e < 4; ++e)
                    if (gk + e < K) vp[e] = A[(size_t)gc * K + gk + e];
            }
        }
    };
    auto write_tile = [&](int buf, const float4& ra, const float4& rb) {
        const float* ap = (const float*)&ra;
        const float* bp = (const float*)&rb;
#pragma unroll
        for (int e = 0; e < 4; ++e) {
            As[buf][sq * 4 + e][srow] = ap[e];
            Bs[buf][sq * 4 + e][srow] = bp[e];
        }
    };

    float blk[4][4] = {};
    float acc[4][4];
    bool first = true;

    const int ntile = (K + 15) / 16;
    {
        float4 ra, rb;
        load_tile(0, ra, rb);
        write_tile(0, ra, rb);
    }
    __syncthreads();

    for (int t = 0; t < ntile; ++t) {
        const int cur = t & 1;
        float4 na, nb;
        const bool have_next = (t + 1 < ntile);
        if (have_next) load_tile((t + 1) * 16, na, nb);   // VMEM in flight
#pragma unroll
        for (int kk = 0; kk < 16; ++kk) {
            float a[4], b[4];
            *(float4*)&a[0] = *(const float4*)&As[cur][kk][ty * 4];
            *(float4*)&b[0] = *(const float4*)&Bs[cur][kk][tx * 4];
#pragma unroll
            for (int i = 0; i < 4; ++i)
#pragma unroll
                for (int j = 0; j < 4; ++j)
                    blk[i][j] = fmaf(a[i], b[j], blk[i][j]);   // strict asc. k
        }
        if (have_next) write_tile(cur ^ 1, na, nb);
        const int knext = (t + 1) * 16;
        if (knext % KC == 0 || knext >= K) {                   // KC fold
            if (first) {
#pragma unroll
                for (int i = 0; i < 4; ++i)
#pragma unroll
                    for (int j = 0; j < 4; ++j) { acc[i][j] = blk[i][j]; blk[i][j] = 0.f; }
                first = false;
            } else {
#pragma unroll
                for (int i = 0; i < 4; ++i)
#pragma unroll
                    for (int j = 0; j < 4; ++j) {
                        acc[i][j] = __fadd_rn(acc[i][j], blk[i][j]);
                        blk[i][j] = 0.f;
                    }
            }
        }
        __syncthreads();
    }

    // epilogue: dist value, float4 store, weighted pass-1 histogram
#pragma unroll
    for (int i = 0; i < 4; ++i) {
        int r = bm + ty * 4 + i;
        if (r >= n) continue;
        float* Crow = C + (size_t)r * n;
        int c = bn + tx * 4;
        float v[4];
#pragma unroll
        for (int e = 0; e < 4; ++e)
            v[e] = epi_apply<2>(acc[i][e], r, c + e, nullptr, wn);
        if (c + 3 < n) {
            float4 s; s.x = v[0]; s.y = v[1]; s.z = v[2]; s.w = v[3];
            *(float4*)(Crow + c) = s;
        } else {
#pragma unroll
            for (int e = 0; e < 4; ++e)
                if (c + e < n) Crow[c + e] = v[e];
        }
#pragma unroll
        for (int e = 0; e < 4; ++e) {
            int cc = c + e;
            if (cc >= n) continue;
            unsigned w = 2u;
            if (diag) {
                if (cc < r) continue;
                if (cc == r) w = 1u;
            }
            unsigned u = __float_as_uint(v[e]);
            unsigned key = (u & 0x80000000u) ? ~u : (u | 0x80000000u);
            atomicAdd(&lh[(((key >> 24) & 0xFFu) << 3) | sub], w);
        }
    }
    __syncthreads();
    unsigned t2 = 0;
#pragma unroll
    for (int s = 0; s < 8; ++s) t2 += lh[(tid << 3) | s];
    partial[blockIdx.x * 256 + tid] = t2;
}

// ---------------------------------------------------------------------------
// Double-buffered fused-KC small GEMM: 64x64 tile, 4x4/thread.
// ---------------------------------------------------------------------------
template<int EPI>
__global__ __launch_bounds__(256, 4)
void gemm_s_k(const float* __restrict__ A, const float* __restrict__ B,
              float* __restrict__ C, int M, int N, int K,
              const float* __restrict__ bias)
{
    __shared__ float As[2][16][68];
    __shared__ float Bs[2][16][68];
    const int tid = threadIdx.x;
    const int tx = tid & 15, ty = tid >> 4;
    const int bm = blockIdx.y * 64, bn = blockIdx.x * 64;

    const int arow = tid >> 2, aq = tid & 3;
    const int bkk = tid >> 4, bc = (tid & 15) * 4;

    auto load_tile = [&](int k0, float4& ra, float4& rb) {
        ra = make_float4(0.f, 0.f, 0.f, 0.f);
        rb = make_float4(0.f, 0.f, 0.f, 0.f);
        {
            int gr = bm + arow, gk = k0 + aq * 4;
            if (gr < M) {
                if (gk + 3 < K) {
                    ra = *(const float4*)(A + (size_t)gr * K + gk);
                } else {
                    float* vp = (float*)&ra;
#pragma unroll
                    for (int e = 0; e < 4; ++e)
                        if (gk + e < K) vp[e] = A[(size_t)gr * K + gk + e];
                }
            }
        }
        {
            int gk = k0 + bkk, gc = bn + bc;
            if (gk < K) {
                if (gc + 3 < N) {
                    rb = *(const float4*)(B + (size_t)gk * N + gc);
                } else {
                    float* vp = (float*)&rb;
#pragma unroll
                    for (int e = 0; e < 4; ++e)
                        if (gc + e < N) vp[e] = B[(size_t)gk * N + gc + e];
                }
            }
        }
    };
    auto write_tile = [&](int buf, const float4& ra, const float4& rb) {
        const float* ap = (const float*)&ra;
#pragma unroll
        for (int e = 0; e < 4; ++e) As[buf][aq * 4 + e][arow] = ap[e];
        *(float4*)&Bs[buf][bkk][bc] = rb;
    };

    float blk[4][4] = {};
    float acc[4][4];
    bool first = true;

    const int ntile = (K + 15) / 16;
    {
        float4 ra, rb;
        load_tile(0, ra, rb);
        write_tile(0, ra, rb);
    }
    __syncthreads();

    for (int t = 0; t < ntile; ++t) {
        const int cur = t & 1;
        float4 na, nb;
        const bool have_next = (t + 1 < ntile);
        if (have_next) load_tile((t + 1) * 16, na, nb);
#pragma unroll
        for (int kk = 0; kk < 16; ++kk) {
            float a[4], b[4];
            *(float4*)&a[0] = *(const float4*)&As[cur][kk][ty * 4];
            *(float4*)&b[0] = *(const float4*)&Bs[cur][kk][tx * 4];
#pragma unroll
            for (int i = 0; i < 4; ++i)
#pragma unroll
                for (int j = 0; j < 4; ++j)
                    blk[i][j] = fmaf(a[i], b[j], blk[i][j]);
        }
        if (have_next) write_tile(cur ^ 1, na, nb);
        const int knext = (t + 1) * 16;
        if (knext % KC == 0 || knext >= K) {
            if (first) {
#pragma unroll
                for (int i = 0; i < 4; ++i)
#pragma unroll
                    for (int j = 0; j < 4; ++j) { acc[i][j] = blk[i][j]; blk[i][j] = 0.f; }
                first = false;
            } else {
#pragma unroll
                for (int i = 0; i < 4; ++i)
#pragma unroll
                    for (int j = 0; j < 4; ++j) {
                        acc[i][j] = __fadd_rn(acc[i][j], blk[i][j]);
                        blk[i][j] = 0.f;
                    }
            }
        }
        __syncthreads();
    }

#pragma unroll
    for (int i = 0; i < 4; ++i) {
        int r = bm + ty * 4 + i;
        if (r >= M) continue;
        float* Crow = C + (size_t)r * N;
        int c = bn + tx * 4;
        float v[4];
#pragma unroll
        for (int e = 0; e < 4; ++e)
            v[e] = epi_apply<EPI>(acc[i][e], r, c + e, bias, nullptr);
        if (c + 3 < N) {
            float4 s; s.x = v[0]; s.y = v[1]; s.z = v[2]; s.w = v[3];
            *(float4*)(Crow + c) = s;
        } else {
#pragma unroll
            for (int e = 0; e < 4; ++e)
                if (c + e < N) Crow[c + e] = v[e];
        }
    }
}

// ---------------------------------------------------------------------------
// Split-K panel GEMM: blockIdx.z = KC panel; raw panel-chain store to P.
// ---------------------------------------------------------------------------
__global__ __launch_bounds__(256, 4)
void gemm_panel_k(const float* __restrict__ A, const float* __restrict__ B,
                  float* __restrict__ P, int M, int N, int K)
{
    __shared__ float As[16][68];
    __shared__ float Bs[16][68];
    const int tid = threadIdx.x;
    const int tx = tid & 15, ty = tid >> 4;
    const int bm = blockIdx.y * 64, bn = blockIdx.x * 64;
    const int kb = blockIdx.z * KC;
    const int kend = (kb + KC < K) ? kb + KC : K;
    float* Pp = P + (size_t)blockIdx.z * M * N;

    float blk[4][4] = {};

    for (int k0 = kb; k0 < kend; k0 += 16) {
        {
            int row = tid >> 2, q = tid & 3;
            int gr = bm + row, gk = k0 + q * 4;
            float4 v = make_float4(0.f, 0.f, 0.f, 0.f);
            if (gr < M) {
                if (gk + 3 < kend) {
                    v = *(const float4*)(A + (size_t)gr * K + gk);
                } else {
                    float* vp = (float*)&v;
#pragma unroll
                    for (int e = 0; e < 4; ++e)
                        if (gk + e < kend) vp[e] = A[(size_t)gr * K + gk + e];
                }
            }
            float* vp = (float*)&v;
#pragma unroll
            for (int e = 0; e < 4; ++e) As[q * 4 + e][row] = vp[e];
        }
        {
            int kk = tid >> 4, c = (tid & 15) * 4;
            int gk = k0 + kk, gc = bn + c;
            float4 v = make_float4(0.f, 0.f, 0.f, 0.f);
            if (gk < kend) {
                if (gc + 3 < N) {
                    v = *(const float4*)(B + (size_t)gk * N + gc);
                } else {
                    float* vp = (float*)&v;
#pragma unroll
                    for (int e = 0; e < 4; ++e)
                        if (gc + e < N) vp[e] = B[(size_t)gk * N + gc + e];
                }
            }
            *(float4*)&Bs[kk][c] = v;
        }
        __syncthreads();
#pragma unroll
        for (int kk = 0; kk < 16; ++kk) {
            float a[4], b[4];
            *(float4*)&a[0] = *(const float4*)&As[kk][ty * 4];
            *(float4*)&b[0] = *(const float4*)&Bs[kk][tx * 4];
#pragma unroll
            for (int i = 0; i < 4; ++i)
#pragma unroll
                for (int j = 0; j < 4; ++j)
                    blk[i][j] = fmaf(a[i], b[j], blk[i][j]);   // strict asc. k
        }
        __syncthreads();
    }

#pragma unroll
    for (int i = 0; i < 4; ++i) {
        int r = bm + ty * 4 + i;
        if (r >= M) continue;
        float* Prow = Pp + (size_t)r * N;
        int c = bn + tx * 4;
        if (c + 3 < N) {
            float4 s; s.x = blk[i][0]; s.y = blk[i][1];
            s.z = blk[i][2]; s.w = blk[i][3];
            *(float4*)(Prow + c) = s;
        } else {
#pragma unroll
            for (int e = 0; e < 4; ++e)
                if (c + e < N) Prow[c + e] = blk[i][e];
        }
    }
}

// ordered panel combine: acc = P0; acc = fadd_rn(acc, P1); ... (frozen fold)
__global__ __launch_bounds__(256)
void combine3_k(const float* __restrict__ P, float* __restrict__ C, size_t nelem)
{
    const size_t i4 = (size_t)(blockIdx.x * 256 + threadIdx.x);
    const size_t stride = (size_t)gridDim.x * 256;
    const size_t n4 = nelem / 4;
    for (size_t i = i4; i < n4; i += stride) {
        float4 a = *(const float4*)(P + i * 4);
        float4 b = *(const float4*)(P + nelem + i * 4);
        float4 c = *(const float4*)(P + 2 * nelem + i * 4);
        float4 o;
        o.x = __fadd_rn(__fadd_rn(a.x, b.x), c.x);
        o.y = __fadd_rn(__fadd_rn(a.y, b.y), c.y);
        o.z = __fadd_rn(__fadd_rn(a.z, b.z), c.z);
        o.w = __fadd_rn(__fadd_rn(a.w, b.w), c.w);
        *(float4*)(C + i * 4) = o;
    }
}

// ---------------------------------------------------------------------------
__global__ __launch_bounds__(256)
void rownorm2_k(const float* __restrict__ X, float* __restrict__ wn)
{
    __shared__ float buf[400];
    __shared__ float leaf[4];
    const int row = blockIdx.x;
    const float* Xr = X + (size_t)row * 400;
    for (int i = threadIdx.x; i < 100; i += 256)
        *(float4*)&buf[i * 4] = *(const float4*)(Xr + i * 4);
    __syncthreads();
    if (threadIdx.x < 4) {
        const int off = (threadIdx.x >> 1) * 200 + ((threadIdx.x & 1) ? 96 : 0);
        const int len = (threadIdx.x & 1) ? 104 : 96;
        leaf[threadIdx.x] = np_pairwise<0>(buf + off, len);
    }
    __syncthreads();
    if (threadIdx.x == 0) {
        float s = __fadd_rn(__fadd_rn(leaf[0], leaf[1]),
                            __fadd_rn(leaf[2], leaf[3]));
        wn[row] = __fsqrt_rn(s);
    }
}

__global__ __launch_bounds__(256)
void rowabs2_k(const float* __restrict__ A, float* __restrict__ rs)
{
    __shared__ float buf[4000];
    __shared__ float leaf[8];
    const int row = blockIdx.x;
    const float* Ar = A + (size_t)row * 4000;
    for (int i = threadIdx.x; i < 1000; i += 256)
        *(float4*)&buf[i * 4] = *(const float4*)(Ar + i * 4);
    __syncthreads();
    if (threadIdx.x < 8) {
        const int off = (threadIdx.x >> 1) * 1000 + ((threadIdx.x & 1) ? 496 : 0);
        const int len = (threadIdx.x & 1) ? 504 : 496;
        leaf[threadIdx.x] = np_pairwise<1>(buf + off, len);
    }
    __syncthreads();
    if (threadIdx.x == 0) {
        float s = __fadd_rn(
            __fadd_rn(__fadd_rn(leaf[0], leaf[1]), __fadd_rn(leaf[2], leaf[3])),
            __fadd_rn(__fadd_rn(leaf[4], leaf[5]), __fadd_rn(leaf[6], leaf[7])));
        rs[row] = fmaxf(s, 1e-12f);
    }
}

// ---------------------------------------------------------------------------
// radix rank-select. state = {prefix, k_remaining}. Also zeroes cnt[].
// ---------------------------------------------------------------------------
__global__ void init_k(unsigned* __restrict__ state, const void* __restrict__ epn,
                       int* __restrict__ cnt)
{
    const int t = blockIdx.x * 256 + threadIdx.x;
    if (t < NN) cnt[t] = 0;
    if (t == 0) {
        int k = ((const int*)epn)[0];
        if (k <= 0 || k > 4000) {
            float f = ((const float*)epn)[0];
            if (f > 0.f && f <= 4000.f) k = (int)f;
            else {
                long long ll = ((const long long*)epn)[0];
                if (ll > 0 && ll <= 4000) k = (int)ll;
                else {
                    double dd = ((const double*)epn)[0];
                    k = (dd > 0.0 && dd <= 4000.0) ? (int)dd : 10;
                }
            }
        }
        state[0] = 0u;
        state[1] = (unsigned)(k * NN);
    }
}

// weighted triangle histogram (passes 2-4); per-block partials.
__global__ __launch_bounds__(256)
void hist_tri_k(const float* __restrict__ dist, unsigned* __restrict__ partial,
                const unsigned* __restrict__ state, int shift, int n)
{
    __shared__ unsigned lh[2048];
    for (int i = threadIdx.x; i < 2048; i += 256) lh[i] = 0;
    __syncthreads();
    const unsigned prefix = state[0];
    const int sub = threadIdx.x & 7;
    const int npair = (n + 1) / 2;
    for (int p = blockIdx.x; p < npair; p += HBLK) {
#pragma unroll
        for (int half = 0; half < 2; ++half) {
            const int i = half ? (n - 1 - p) : p;
            if (half && i == p) break;
            const float* row = dist + (size_t)i * n;
            for (int j = i + threadIdx.x; j < n; j += 256) {
                unsigned u = __float_as_uint(row[j]);
                unsigned key = (u & 0x80000000u) ? ~u : (u | 0x80000000u);
                bool ok = ((key >> (shift + 8)) == prefix);
                if (ok) atomicAdd(&lh[((((key >> shift) & 0xFFu)) << 3) | sub],
                                  (j == i) ? 1u : 2u);
            }
        }
    }
    __syncthreads();
    unsigned t = 0;
#pragma unroll
    for (int s = 0; s < 8; ++s) t += lh[(threadIdx.x << 3) | s];
    partial[blockIdx.x * 256 + threadIdx.x] = t;
}

// parallel partial reduction: block b = bin b; threads stride-sum partials.
__global__ __launch_bounds__(256)
void reduce_k(const unsigned* __restrict__ partial, int nparts,
              unsigned* __restrict__ hist256)
{
    const int bin = blockIdx.x;
    const int tid = threadIdx.x;
    unsigned s = 0;
    for (int i = tid; i < nparts; i += 256)
        s += partial[(size_t)i * 256 + bin];
    __shared__ unsigned sh[256];
    sh[tid] = s;
    __syncthreads();
    for (int off = 128; off > 0; off >>= 1) {
        if (tid < off) sh[tid] += sh[tid + off];
        __syncthreads();
    }
    if (tid == 0) hist256[bin] = sh[0];
}

// tiny 256-bin scan + radix descend
__global__ __launch_bounds__(256)
void scan256_k(const unsigned* __restrict__ hist256, unsigned* __restrict__ state,
               int shift, float* __restrict__ param)
{
    const int tid = threadIdx.x;
    unsigned h = hist256[tid];
    __shared__ unsigned sh[256];
    sh[tid] = h;
    __syncthreads();
    for (int off = 1; off < 256; off <<= 1) {
        unsigned v = (tid >= off) ? sh[tid - off] : 0;
        __syncthreads();
        sh[tid] += v;
        __syncthreads();
    }
    const unsigned incl = sh[tid], excl = incl - h;
    const unsigned krem = state[1];
    if (krem >= excl && krem < incl) {
        unsigned np = (state[0] << 8) | (unsigned)tid;
        state[0] = np;
        state[1] = krem - excl;
        if (shift == 0) {
            unsigned u = (np & 0x80000000u) ? (np ^ 0x80000000u) : ~np;
            *param = __uint_as_float(u);
        }
    }
}

// ---------------------------------------------------------------------------
__device__ inline float thr_f(float d, int i, int j, float p)
{
    float a = (d <= p && i != j) ? __fsub_rn(1.0f, d) : 0.0f;
    return (i == j) ? 1.0f : a;
}

// 64-aligned threshold upper tiles + mirror lower via LDS transpose;
// per-row nonzero counts via ballot (identical to count_k on stored values).
__global__ __launch_bounds__(256)
void symthresh_mirror_k(float* __restrict__ adj, const float* __restrict__ param,
                        int* __restrict__ cnt, int n)
{
    __shared__ float TB[64][65];
    const float p = *param;
    const int nt = (n + 63) >> 6;
    int bi = 0, rem = blockIdx.x;
    while (rem >= nt - bi) { rem -= nt - bi; ++bi; }
    const int bj = bi + rem;
    const int tid = threadIdx.x;
    const int lane = tid & 63;
    const int r0i = bi * 64, r0j = bj * 64;

#pragma unroll
    for (int it = 0; it < 16; ++it) {
        int idx = tid + it * 256;
        int q = idx >> 6, c = idx & 63;
        int gr = r0i + q, gc = r0j + c;
        bool inb = (gr < n && gc < n);
        float a = 0.f;
        if (inb) {
            a = thr_f(adj[(size_t)gr * n + gc], gr, gc, p);
            adj[(size_t)gr * n + gc] = a;
            TB[q][c] = a;
        }
        unsigned long long m = __ballot(inb && a != 0.0f);
        if (lane == 0 && gr < n) atomicAdd(&cnt[gr], (int)__popcll(m));
    }
    __syncthreads();
    if (bi != bj) {
#pragma unroll
        for (int it = 0; it < 16; ++it) {
            int idx = tid + it * 256;
            int q = idx >> 6, c = idx & 63;
            int gr = r0j + q, gc = r0i + c;
            bool inb = (gr < n && gc < n);
            float a = 0.f;
            if (inb) {
                a = TB[c][q];
                adj[(size_t)gr * n + gc] = a;
            }
            unsigned long long m = __ballot(inb && a != 0.0f);
            if (lane == 0 && gr < n) atomicAdd(&cnt[gr], (int)__popcll(m));
        }
    }
}

__global__ __launch_bounds__(256)
void norm_k(float* __restrict__ adj, const float* __restrict__ rs, int n)
{
    const int i = blockIdx.y;
    const int j = blockIdx.x * 256 + threadIdx.x;
    if (j >= n) return;
    const size_t idx = (size_t)i * n + j;
    adj[idx] = __fdiv_rn(adj[idx], rs[i]);
}

// ---------------------------------------------------------------------------
__global__ __launch_bounds__(256)
void count_k(const float* __restrict__ A, int* __restrict__ cnt, int n)
{
    const int gw = (blockIdx.x * blockDim.x + threadIdx.x) >> 6;
    if (gw >= n) return;
    const int lane = threadIdx.x & 63;
    int c = 0;
    for (int k0 = 0; k0 < n; k0 += 64) {
        int k = k0 + lane;
        bool nz = (k < n) && (A[(size_t)gw * n + k] != 0.0f);
        unsigned long long m = __ballot(nz);
        c += (int)__popcll(m);
    }
    if (lane == 0) cnt[gw] = c;
}

__global__ __launch_bounds__(1024)
void scanrows_k(const int* __restrict__ cnt, int* __restrict__ roff)
{
    const int t = threadIdx.x;
    int vals[4];
    int s0 = 0;
#pragma unroll
    for (int e = 0; e < 4; ++e) {
        int r = t * 4 + e;
        vals[e] = (r < NN) ? cnt[r] : 0;
        s0 += vals[e];
    }
    __shared__ int sh[1024];
    sh[t] = s0;
    __syncthreads();
    for (int off = 1; off < 1024; off <<= 1) {
        int v = (t >= off) ? sh[t - off] : 0;
        __syncthreads();
        sh[t] += v;
        __syncthreads();
    }
    int excl = sh[t] - s0;
#pragma unroll
    for (int e = 0; e < 4; ++e) {
        int r = t * 4 + e;
        if (r <= NN) roff[r] = excl;
        excl += vals[e];
    }
    if (t == 1023) roff[NN] = sh[1023];
}

template<bool DIV>
__global__ __launch_bounds__(256)
void fill_k(const float* __restrict__ A, const int* __restrict__ roff,
            const float* __restrict__ rs, int* __restrict__ ridx,
            float* __restrict__ rval, int n)
{
    const int gw = (blockIdx.x * blockDim.x + threadIdx.x) >> 6;
    if (gw >= n) return;
    const int lane = threadIdx.x & 63;
    const float r = DIV ? rs[gw] : 1.0f;
    int base = roff[gw];
    const unsigned long long ltmask = (lane == 63) ? ~0ULL >> 1
                                                   : ((1ULL << lane) - 1);
    for (int k0 = 0; k0 < n; k0 += 64) {
        int k = k0 + lane;
        float v = (k < n) ? A[(size_t)gw * n + k] : 0.f;
        bool nz = (v != 0.0f);
        unsigned long long m = __ballot(nz);
        if (nz) {
            int pos = base + (int)__popcll(m & ltmask);
            ridx[pos] = k;
            rval[pos] = DIV ? __fdiv_rn(v, r) : v;
        }
        base += (int)__popcll(m);
    }
}

// WN: also compute wn[r] = sqrt_rn(np_pairwise<0>(H row)) in the epilogue.
template<bool WN>
__global__ __launch_bounds__(256)
void spmm_k(const int* __restrict__ roff, const int* __restrict__ ridx,
            const float* __restrict__ rval, const float* __restrict__ T,
            const float* __restrict__ bias, float* __restrict__ H, int ncols,
            float* __restrict__ wn)
{
    __shared__ int ks[128];
    __shared__ float vs[128];
    __shared__ float buf[512];
    __shared__ float leaf[4];
    const int r = blockIdx.x;
    const int tid = threadIdx.x;
    const int c0 = tid, c1 = tid + 256;
    const bool ok0 = c0 < ncols, ok1 = c1 < ncols;
    float acc0 = 0.f, blk0 = 0.f, acc1 = 0.f, blk1 = 0.f;
    int nb = KC;
    const int s = roff[r], e = roff[r + 1];
    for (int base = s; base < e; base += 128) {
        const int m = (e - base < 128) ? (e - base) : 128;
        __syncthreads();
        if (tid < m) { ks[tid] = ridx[base + tid]; vs[tid] = rval[base + tid]; }
        __syncthreads();
        for (int t = 0; t < m; ++t) {
            const int k = ks[t];
            const float v = vs[t];
            while (k >= nb) {
                acc0 = __fadd_rn(acc0, blk0); blk0 = 0.f;
                acc1 = __fadd_rn(acc1, blk1); blk1 = 0.f;
                nb += KC;
            }
            const float* Tr = T + (size_t)k * ncols;
            if (ok0) blk0 = fmaf(v, Tr[c0], blk0);
            if (ok1) blk1 = fmaf(v, Tr[c1], blk1);
        }
    }
    acc0 = __fadd_rn(acc0, blk0);
    acc1 = __fadd_rn(acc1, blk1);
    float h0 = 0.f, h1 = 0.f;
    if (ok0) {
        float s0 = __fadd_rn(acc0, bias[c0]);
        h0 = (s0 >= 0.f) ? s0 : __fmul_rn(LEAKY, s0);
        H[(size_t)r * ncols + c0] = h0;
    }
    if (ok1) {
        float s1 = __fadd_rn(acc1, bias[c1]);
        h1 = (s1 >= 0.f) ? s1 : __fmul_rn(LEAKY, s1);
        H[(size_t)r * ncols + c1] = h1;
    }
    if (WN) {
        if (ok0) buf[c0] = h0;
        if (ok1) buf[c1] = h1;
        __syncthreads();
        if (tid < 4) {
            const int off = (tid >> 1) * 200 + ((tid & 1) ? 96 : 0);
            const int len = (tid & 1) ? 104 : 96;
            leaf[tid] = np_pairwise<0>(buf + off, len);
        }
        __syncthreads();
        if (tid == 0) {
            float s2 = __fadd_rn(__fadd_rn(leaf[0], leaf[1]),
                                 __fadd_rn(leaf[2], leaf[3]));
            wn[r] = __fsqrt_rn(s2);
        }
    }
}

// ---------------------------------------------------------------------------
template<int EPI, bool TRANSB, bool FIRST, bool LAST>
__global__ __launch_bounds__(256, 4)
void gemm_pass_k(const float* __restrict__ A, const float* __restrict__ B,
                 float* __restrict__ C, int M, int N, int K, int kb, int kend,
                 const float* __restrict__ bias, const float* __restrict__ wn)
{
    __shared__ float As[16][132];
    __shared__ float Bs[16][132];
    const int tid = threadIdx.x;
    const int tx = tid & 15, ty = tid >> 4;
    const int bm = blockIdx.y * 128, bn = blockIdx.x * 128;

    float blk[8][8] = {};

    for (int k0 = kb; k0 < kend; k0 += 16) {
#pragma unroll
        for (int it = 0; it < 2; ++it) {
            int idx = tid + it * 256;
            int row = idx >> 2, q = idx & 3;
            int gr = bm + row, gk = k0 + q * 4;
            float4 v = make_float4(0.f, 0.f, 0.f, 0.f);
            if (gr < M) {
                if (gk + 3 < kend) {
                    v = *(const float4*)(A + (size_t)gr * K + gk);
                } else {
                    float* vp = (float*)&v;
#pragma unroll
                    for (int e = 0; e < 4; ++e)
                        if (gk + e < kend) vp[e] = A[(size_t)gr * K + gk + e];
                }
            }
            float* vp = (float*)&v;
#pragma unroll
            for (int e = 0; e < 4; ++e) As[q * 4 + e][row] = vp[e];
        }
        if (!TRANSB) {
#pragma unroll
            for (int it = 0; it < 2; ++it) {
                int idx = tid + it * 256;
                int kk = idx >> 5, cq = idx & 31;
                int gk = k0 + kk, c = cq * 4, gc = bn + c;
                float4 v = make_float4(0.f, 0.f, 0.f, 0.f);
                if (gk < kend) {
                    if (gc + 3 < N) {
                        v = *(const float4*)(B + (size_t)gk * N + gc);
                    } else {
                        float* vp = (float*)&v;
#pragma unroll
                        for (int e = 0; e < 4; ++e)
                            if (gc + e < N) vp[e] = B[(size_t)gk * N + gc + e];
                    }
                }
                *(float4*)&Bs[kk][c] = v;
            }
        } else {
#pragma unroll
            for (int it = 0; it < 2; ++it) {
                int idx = tid + it * 256;
                int row = idx >> 2, q = idx & 3;
                int gc = bn + row, gk = k0 + q * 4;
                float4 v = make_float4(0.f, 0.f, 0.f, 0.f);
                if (gc < N) {
                    if (gk + 3 < kend) {
                        v = *(const float4*)(B + (size_t)gc * K + gk);
                    } else {
                        float* vp = (float*)&v;
#pragma unroll
                        for (int e = 0; e < 4; ++e)
                            if (gk + e < kend) vp[e] = B[(size_t)gc * K + gk + e];
                    }
                }
                float* vp = (float*)&v;
#pragma unroll
                for (int e = 0; e < 4; ++e) Bs[q * 4 + e][row] = vp[e];
            }
        }
        __syncthreads();
#pragma unroll
        for (int kk = 0; kk < 16; ++kk) {
            float a[8], b[8];
            *(float4*)&a[0] = *(const float4*)&As[kk][ty * 4];
            *(float4*)&a[4] = *(const float4*)&As[kk][ty * 4 + 64];
            *(float4*)&b[0] = *(const float4*)&Bs[kk][tx * 4];
            *(float4*)&b[4] = *(const float4*)&Bs[kk][tx * 4 + 64];
#pragma unroll
            for (int i = 0; i < 8; ++i)
#pragma unroll
                for (int j = 0; j < 8; ++j)
                    blk[i][j] = fmaf(a[i], b[j], blk[i][j]);
        }
        __syncthreads();
    }

#pragma unroll
    for (int i = 0; i < 8; ++i) {
        int r = bm + ty * 4 + (i & 3) + (i >> 2) * 64;
        if (r >= M) continue;
        float* Crow = C + (size_t)r * N;
#pragma unroll
        for (int h = 0; h < 2; ++h) {
            int c = bn + tx * 4 + h * 64;
            float v[4];
#pragma unroll
            for (int e = 0; e < 4; ++e) v[e] = blk[i][h * 4 + e];
            if (c + 3 < N) {
                if (!FIRST) {
                    float4 o = *(const float4*)(Crow + c);
                    v[0] = __fadd_rn(o.x, v[0]); v[1] = __fadd_rn(o.y, v[1]);
                    v[2] = __fadd_rn(o.z, v[2]); v[3] = __fadd_rn(o.w, v[3]);
                }
                if (LAST) {
#pragma unroll
                    for (int e = 0; e < 4; ++e)
                        v[e] = epi_apply<EPI>(v[e], r, c + e, bias, wn);
                }
                float4 s; s.x = v[0]; s.y = v[1]; s.z = v[2]; s.w = v[3];
                *(float4*)(Crow + c) = s;
            } else {
#pragma unroll
                for (int e = 0; e < 4; ++e) {
                    if (c + e >= N) continue;
                    float vv = v[e];
                    if (!FIRST) vv = __fadd_rn(Crow[c + e], vv);
                    if (LAST) vv = epi_apply<EPI>(vv, r, c + e, bias, wn);
                    Crow[c + e] = vv;
                }
            }
        }
    }
}

template<int EPI, bool TRANSB>
static void run_gemm(const float* A, const float* B, float* C,
                     int M, int N, int K, const float* bias, const float* wn,
                     hipStream_t stream)
{
    const int nb = (K + KC - 1) / KC;
    const dim3 grid((N + 127) / 128, (M + 127) / 128);
    for (int p = 0; p < nb; ++p) {
        const int kb = p * KC;
        const int kend = (kb + KC < K) ? kb + KC : K;
        const bool first = (p == 0), last = (p == nb - 1);
        if (first && last)
            gemm_pass_k<EPI, TRANSB, true, true><<<grid, 256, 0, stream>>>(
                A, B, C, M, N, K, kb, kend, bias, wn);
        else if (first)
            gemm_pass_k<EPI, TRANSB, true, false><<<grid, 256, 0, stream>>>(
                A, B, C, M, N, K, kb, kend, bias, wn);
        else if (last)
            gemm_pass_k<EPI, TRANSB, false, true><<<grid, 256, 0, stream>>>(
                A, B, C, M, N, K, kb, kend, bias, wn);
        else
            gemm_pass_k<EPI, TRANSB, false, false><<<grid, 256, 0, stream>>>(
                A, B, C, M, N, K, kb, kend, bias, wn);
    }
}

extern "C" void kernel_launch(void* const* d_in, const int* in_sizes, int n_in,
                              void* d_out, int out_size, void* d_ws, size_t ws_size,
                              hipStream_t stream)
{
    const void*  epn  = d_in[0];
    const float* x    = (const float*)d_in[1];
    const float* adj0 = (const float*)d_in[2];
    const float* w1   = (const float*)d_in[3];
    const float* b1   = (const float*)d_in[4];
    const float* w2   = (const float*)d_in[5];
    const float* b2   = (const float*)d_in[6];
    const float* w3   = (const float*)d_in[7];
    const float* b3   = (const float*)d_in[8];
    float* out = (float*)d_out;

    char* ws = (char*)d_ws;
    float*    dist    = (float*)   ws;                     // 64,000,000
    float*    Tbuf    = (float*)  (ws + 64000000);         //  6,400,000
    float*    H1      = (float*)  (ws + 70400000);         //  6,400,000
    float*    H2      = (float*)  (ws + 76800000);         //  6,400,000
    float*    wn      = (float*)  (ws + 83200000);         //     16,000
    float*    rs      = (float*)  (ws + 83216000);         //     16,000
    unsigned* state   = (unsigned*)(ws + 83232000);        //          8
    float*    param   = (float*)  (ws + 83232008);         //          4
    unsigned* hist256 = (unsigned*)(ws + 83232064);        //      1,024
    unsigned* partial = (unsigned*)(ws + 83233088);        //  2,064,384 (2016x256)
    int*      cnt     = (int*)    (ws + 85297472);         //     16,000
    int*      roff    = (int*)    (ws + 85313472);         //     16,008
    int*      ridx    = (int*)    (ws + 85329480);         // 16,000,000
    float*    rval    = (float*)  (ws + 101329480);        // 16,000,000
    float*    panels  = (float*)  (ws + 85329480);         // alias: 3x6.4MB,
                                  // live only before layer-1 CSR build
    const bool use_csr = (ws_size >= 117329480ULL + 64);

    const int gsN = (NN + 63) / 64;   // 63
    const int nt64 = (NN + 63) / 64;
    const int nsym64 = nt64 * (nt64 + 1) / 2;   // == NPART1 == 2016

    auto genadj = [&](const float* H, bool have_wn) {
        if (!have_wn)
            rownorm2_k<<<NN, 256, 0, stream>>>(H, wn);
        gemm_tri64_k<<<nsym64, 256, 0, stream>>>(H, dist, partial, NN, 400, wn);
        init_k<<<16, 256, 0, stream>>>(state, epn, cnt);
        reduce_k<<<256, 256, 0, stream>>>(partial, NPART1, hist256);
        scan256_k<<<1, 256, 0, stream>>>(hist256, state, 24, param);
        for (int p = 1; p < 4; ++p) {
            const int shift = 24 - 8 * p;
            hist_tri_k<<<HBLK, 256, 0, stream>>>(dist, partial, state, shift, NN);
            reduce_k<<<256, 256, 0, stream>>>(partial, HBLK, hist256);
            scan256_k<<<1, 256, 0, stream>>>(hist256, state, shift, param);
        }
        symthresh_mirror_k<<<nsym64, 256, 0, stream>>>(dist, param, cnt, NN);
        rowabs2_k<<<NN, 256, 0, stream>>>(dist, rs);
    };

    auto aggregate_pre = [&](const float* Aadj, const float* Tm,
                             const float* bias, float* Hout, int ncols,
                             bool want_wn) {
        if (use_csr) {
            count_k<<<(NN + 3) / 4, 256, 0, stream>>>(Aadj, cnt, NN);
            scanrows_k<<<1, 1024, 0, stream>>>(cnt, roff);
            fill_k<false><<<(NN + 3) / 4, 256, 0, stream>>>(Aadj, roff, nullptr,
                                                            ridx, rval, NN);
            if (want_wn)
                spmm_k<true><<<NN, 256, 0, stream>>>(roff, ridx, rval, Tm, bias,
                                                     Hout, ncols, wn);
            else
                spmm_k<false><<<NN, 256, 0, stream>>>(roff, ridx, rval, Tm, bias,
                                                      Hout, ncols, nullptr);
        } else {
            run_gemm<1, false>(Aadj, Tm, Hout, NN, ncols, NN, bias,
                               nullptr, stream);
        }
    };

    auto aggregate_rs = [&](float* Aadj, const float* Tm,
                            const float* bias, float* Hout, int ncols,
                            bool want_wn) {
        if (use_csr) {
            scanrows_k<<<1, 1024, 0, stream>>>(cnt, roff);
            fill_k<true><<<(NN + 3) / 4, 256, 0, stream>>>(Aadj, roff, rs,
                                                           ridx, rval, NN);
            if (want_wn)
                spmm_k<true><<<NN, 256, 0, stream>>>(roff, ridx, rval, Tm, bias,
                                                     Hout, ncols, wn);
            else
                spmm_k<false><<<NN, 256, 0, stream>>>(roff, ridx, rval, Tm, bias,
                                                      Hout, ncols, nullptr);
        } else {
            norm_k<<<dim3((NN + 255) / 256, NN), 256, 0, stream>>>(Aadj, rs, NN);
            run_gemm<1, false>(Aadj, Tm, Hout, NN, ncols, NN, bias,
                               nullptr, stream);
        }
    };

    // ---- Layer 1: Tbuf = x@w1 (split-K over 3 KC panels, ordered combine)
    if (use_csr) {
        gemm_panel_k<<<dim3((400 + 63) / 64, gsN, 3), 256, 0, stream>>>(
            x, w1, panels, NN, 400, 1000);
        combine3_k<<<1024, 256, 0, stream>>>(panels, Tbuf, (size_t)NN * 400);
    } else {
        gemm_s_k<0><<<dim3((400 + 63) / 64, gsN), 256, 0, stream>>>(
            x, w1, Tbuf, NN, 400, 1000, nullptr);
    }
    aggregate_pre(adj0, Tbuf, b1, H1, 400, use_csr);

    // ---- gen_adj(H1) + Layer 2 (+wn of H2)
    genadj(H1, use_csr);
    gemm_s_k<0><<<dim3((400 + 63) / 64, gsN), 256, 0, stream>>>(
        H1, w2, Tbuf, NN, 400, 400, nullptr);
    aggregate_rs(dist, Tbuf, b2, H2, 400, use_csr);

    // ---- gen_adj(H2) + Layer 3
    genadj(H2, use_csr);
    gemm_s_k<0><<<dim3((200 + 63) / 64, gsN), 256, 0, stream>>>(
        H2, w3, Tbuf, NN, 200, 400, nullptr);
    aggregate_rs(dist, Tbuf, b3, out, 200, false);
}

// Round 22
// 859.996 us; speedup vs baseline: 2.7325x; 2.7325x over previous
//
#include <hip/hip_runtime.h>
#include <math.h>

#define NN 4000
#define KC 384      // OpenBLAS SGEMM_DEFAULT_Q — fold granularity (bit-frozen)
#define LEAKY 0.25f
#define HBLK 1000   // histogram blocks (passes 2-4)
#define NPART1 2016 // tri64 blocks = partial rows for pass 1

// ===========================================================================
// Bit-frozen arithmetic (verified R6-R21, absmax must remain 0.001953125):
//   - per-output dot: blk = fmaf(a_k,b_k,blk) strict ascending k within each
//     KC=384 block; first block's total COPIED to acc, later blocks
//     acc = __fadd_rn(acc, blk) in order (OpenBLAS store-then-add).
//   - reductions: numpy pairwise_sum tree; elementwise: *_rn intrinsics.
// R22: exact revert to the measured-best R20 configuration (861us).
// R21's double-buffer spilled prefetch regs to scratch (WRITE 34MB->2.28GB,
// VALUBusy 9%) — hand pipelining falsified; implicit wave overlap at
// 4 blocks/CU is the optimum for this shape.
// ===========================================================================

template<int EPI>
__device__ inline float epi_apply(float v, int r, int c,
                                  const float* __restrict__ bias,
                                  const float* __restrict__ wn)
{
    if (EPI == 1) {
        float s = __fadd_rn(v, bias[c]);
        return (s >= 0.f) ? s : __fmul_rn(LEAKY, s);
    }
    if (EPI == 2) {
        float den = fmaxf(__fmul_rn(wn[r], wn[c]), 1e-8f);
        return __fsub_rn(1.0f, __fdiv_rn(v, den));
    }
    return v;
}

// ---------------------------------------------------------------------------
// numpy pairwise_sum exact replica. XF=0: fl(v*v); XF=1: |v|.
// ---------------------------------------------------------------------------
template<int XF>
__device__ float xf(float v)
{
    if (XF == 0) return __fmul_rn(v, v);
    return fabsf(v);
}

template<int XF>
__device__ float np_pairwise(const float* a, int n)
{
    if (n < 8) {
        float r = 0.f;
        for (int i = 0; i < n; ++i) r = __fadd_rn(r, xf<XF>(a[i]));
        return r;
    }
    if (n <= 128) {
        float r[8];
#pragma unroll
        for (int j = 0; j < 8; ++j) r[j] = xf<XF>(a[j]);
        int i = 8;
        const int lim = n - (n & 7);
        for (; i < lim; i += 8)
#pragma unroll
            for (int j = 0; j < 8; ++j) r[j] = __fadd_rn(r[j], xf<XF>(a[i + j]));
        float res = __fadd_rn(__fadd_rn(__fadd_rn(r[0], r[1]), __fadd_rn(r[2], r[3])),
                              __fadd_rn(__fadd_rn(r[4], r[5]), __fadd_rn(r[6], r[7])));
        for (; i < n; ++i) res = __fadd_rn(res, xf<XF>(a[i]));
        return res;
    }
    int n2 = (n / 2) & ~7;
    return __fadd_rn(np_pairwise<XF>(a, n2), np_pairwise<XF>(a + n2, n - n2));
}

// ---------------------------------------------------------------------------
// Fused-KC 64x64-tile triangular dist GEMM (EPI=2), tile pairs bi<=bj.
// 4x4/thread, float4 stores. Epilogue: radix pass-1 weighted histogram.
// (R16/R20 configuration: separate lh, launch_bounds(256,4) — 4 blocks/CU.)
// ---------------------------------------------------------------------------
__global__ __launch_bounds__(256, 4)
void gemm_tri64_k(const float* __restrict__ A, float* __restrict__ C,
                  unsigned* __restrict__ partial, int n, int K,
                  const float* __restrict__ wn)
{
    __shared__ float As[16][68];
    __shared__ float Bs[16][68];
    __shared__ unsigned lh[2048];   // 256 bins x 8 copies (pass-1 hist)
    const int tid = threadIdx.x;
    const int tx = tid & 15, ty = tid >> 4;
    const int sub = tid & 7;
    const int nt = (n + 63) >> 6;
    int bi = 0, rem = blockIdx.x;
    while (rem >= nt - bi) { rem -= nt - bi; ++bi; }
    const int bm = bi * 64, bn = (bi + rem) * 64;
    const bool diag = (rem == 0);

    for (int i = tid; i < 2048; i += 256) lh[i] = 0;

    float blk[4][4] = {};
    float acc[4][4];
    bool first = true;

    for (int kb = 0; kb < K; kb += KC) {
        const int kend = (kb + KC < K) ? kb + KC : K;
        for (int k0 = kb; k0 < kend; k0 += 16) {
            {
                int row = tid >> 2, q = tid & 3;
                int gr = bm + row, gk = k0 + q * 4;
                float4 v = make_float4(0.f, 0.f, 0.f, 0.f);
                if (gr < n) {
                    if (gk + 3 < kend) {
                        v = *(const float4*)(A + (size_t)gr * K + gk);
                    } else {
                        float* vp = (float*)&v;
#pragma unroll
                        for (int e = 0; e < 4; ++e)
                            if (gk + e < kend) vp[e] = A[(size_t)gr * K + gk + e];
                    }
                }
                float* vp = (float*)&v;
#pragma unroll
                for (int e = 0; e < 4; ++e) As[q * 4 + e][row] = vp[e];
            }
            {
                int row = tid >> 2, q = tid & 3;
                int gc = bn + row, gk = k0 + q * 4;
                float4 v = make_float4(0.f, 0.f, 0.f, 0.f);
                if (gc < n) {
                    if (gk + 3 < kend) {
                        v = *(const float4*)(A + (size_t)gc * K + gk);
                    } else {
                        float* vp = (float*)&v;
#pragma unroll
                        for (int e = 0; e < 4; ++e)
                            if (gk + e < kend) vp[e] = A[(size_t)gc * K + gk + e];
                    }
                }
                float* vp = (float*)&v;
#pragma unroll
                for (int e = 0; e < 4; ++e) Bs[q * 4 + e][row] = vp[e];
            }
            __syncthreads();
#pragma unroll
            for (int kk = 0; kk < 16; ++kk) {
                float a[4], b[4];
                *(float4*)&a[0] = *(const float4*)&As[kk][ty * 4];
                *(float4*)&b[0] = *(const float4*)&Bs[kk][tx * 4];
#pragma unroll
                for (int i = 0; i < 4; ++i)
#pragma unroll
                    for (int j = 0; j < 4; ++j)
                        blk[i][j] = fmaf(a[i], b[j], blk[i][j]);   // strict asc. k
            }
            __syncthreads();
        }
        if (first) {
#pragma unroll
            for (int i = 0; i < 4; ++i)
#pragma unroll
                for (int j = 0; j < 4; ++j) { acc[i][j] = blk[i][j]; blk[i][j] = 0.f; }
            first = false;
        } else {
#pragma unroll
            for (int i = 0; i < 4; ++i)
#pragma unroll
                for (int j = 0; j < 4; ++j) {
                    acc[i][j] = __fadd_rn(acc[i][j], blk[i][j]);
                    blk[i][j] = 0.f;
                }
        }
    }

    // epilogue: dist value, float4 store, weighted pass-1 histogram
#pragma unroll
    for (int i = 0; i < 4; ++i) {
        int r = bm + ty * 4 + i;
        if (r >= n) continue;
        float* Crow = C + (size_t)r * n;
        int c = bn + tx * 4;
        float v[4];
#pragma unroll
        for (int e = 0; e < 4; ++e)
            v[e] = epi_apply<2>(acc[i][e], r, c + e, nullptr, wn);
        if (c + 3 < n) {
            float4 s; s.x = v[0]; s.y = v[1]; s.z = v[2]; s.w = v[3];
            *(float4*)(Crow + c) = s;
        } else {
#pragma unroll
            for (int e = 0; e < 4; ++e)
                if (c + e < n) Crow[c + e] = v[e];
        }
#pragma unroll
        for (int e = 0; e < 4; ++e) {
            int cc = c + e;
            if (cc >= n) continue;
            unsigned w = 2u;
            if (diag) {
                if (cc < r) continue;
                if (cc == r) w = 1u;
            }
            unsigned u = __float_as_uint(v[e]);
            unsigned key = (u & 0x80000000u) ? ~u : (u | 0x80000000u);
            atomicAdd(&lh[(((key >> 24) & 0xFFu) << 3) | sub], w);
        }
    }
    __syncthreads();
    unsigned t = 0;
#pragma unroll
    for (int s = 0; s < 8; ++s) t += lh[(tid << 3) | s];
    partial[blockIdx.x * 256 + tid] = t;
}

// ---------------------------------------------------------------------------
// Fused-KC small GEMM: 64x64 tile, 256 threads, 4x4/thread.
// ---------------------------------------------------------------------------
template<int EPI>
__global__ __launch_bounds__(256, 4)
void gemm_s_k(const float* __restrict__ A, const float* __restrict__ B,
              float* __restrict__ C, int M, int N, int K,
              const float* __restrict__ bias)
{
    __shared__ float As[16][68];
    __shared__ float Bs[16][68];
    const int tid = threadIdx.x;
    const int tx = tid & 15, ty = tid >> 4;
    const int bm = blockIdx.y * 64, bn = blockIdx.x * 64;

    float blk[4][4] = {};
    float acc[4][4];
    bool first = true;

    for (int kb = 0; kb < K; kb += KC) {
        const int kend = (kb + KC < K) ? kb + KC : K;
        for (int k0 = kb; k0 < kend; k0 += 16) {
            {
                int row = tid >> 2, q = tid & 3;
                int gr = bm + row, gk = k0 + q * 4;
                float4 v = make_float4(0.f, 0.f, 0.f, 0.f);
                if (gr < M) {
                    if (gk + 3 < kend) {
                        v = *(const float4*)(A + (size_t)gr * K + gk);
                    } else {
                        float* vp = (float*)&v;
#pragma unroll
                        for (int e = 0; e < 4; ++e)
                            if (gk + e < kend) vp[e] = A[(size_t)gr * K + gk + e];
                    }
                }
                float* vp = (float*)&v;
#pragma unroll
                for (int e = 0; e < 4; ++e) As[q * 4 + e][row] = vp[e];
            }
            {
                int kk = tid >> 4, c = (tid & 15) * 4;
                int gk = k0 + kk, gc = bn + c;
                float4 v = make_float4(0.f, 0.f, 0.f, 0.f);
                if (gk < kend) {
                    if (gc + 3 < N) {
                        v = *(const float4*)(B + (size_t)gk * N + gc);
                    } else {
                        float* vp = (float*)&v;
#pragma unroll
                        for (int e = 0; e < 4; ++e)
                            if (gc + e < N) vp[e] = B[(size_t)gk * N + gc + e];
                    }
                }
                *(float4*)&Bs[kk][c] = v;
            }
            __syncthreads();
#pragma unroll
            for (int kk = 0; kk < 16; ++kk) {
                float a[4], b[4];
                *(float4*)&a[0] = *(const float4*)&As[kk][ty * 4];
                *(float4*)&b[0] = *(const float4*)&Bs[kk][tx * 4];
#pragma unroll
                for (int i = 0; i < 4; ++i)
#pragma unroll
                    for (int j = 0; j < 4; ++j)
                        blk[i][j] = fmaf(a[i], b[j], blk[i][j]);
            }
            __syncthreads();
        }
        if (first) {
#pragma unroll
            for (int i = 0; i < 4; ++i)
#pragma unroll
                for (int j = 0; j < 4; ++j) { acc[i][j] = blk[i][j]; blk[i][j] = 0.f; }
            first = false;
        } else {
#pragma unroll
            for (int i = 0; i < 4; ++i)
#pragma unroll
                for (int j = 0; j < 4; ++j) {
                    acc[i][j] = __fadd_rn(acc[i][j], blk[i][j]);
                    blk[i][j] = 0.f;
                }
        }
    }

#pragma unroll
    for (int i = 0; i < 4; ++i) {
        int r = bm + ty * 4 + i;
        if (r >= M) continue;
        float* Crow = C + (size_t)r * N;
        int c = bn + tx * 4;
        float v[4];
#pragma unroll
        for (int e = 0; e < 4; ++e)
            v[e] = epi_apply<EPI>(acc[i][e], r, c + e, bias, nullptr);
        if (c + 3 < N) {
            float4 s; s.x = v[0]; s.y = v[1]; s.z = v[2]; s.w = v[3];
            *(float4*)(Crow + c) = s;
        } else {
#pragma unroll
            for (int e = 0; e < 4; ++e)
                if (c + e < N) Crow[c + e] = v[e];
        }
    }
}

// ---------------------------------------------------------------------------
// Split-K panel GEMM: blockIdx.z = KC panel; raw panel-chain store to P.
// Same staging/chain as gemm_s_k => per-panel sums bit-identical.
// ---------------------------------------------------------------------------
__global__ __launch_bounds__(256, 4)
void gemm_panel_k(const float* __restrict__ A, const float* __restrict__ B,
                  float* __restrict__ P, int M, int N, int K)
{
    __shared__ float As[16][68];
    __shared__ float Bs[16][68];
    const int tid = threadIdx.x;
    const int tx = tid & 15, ty = tid >> 4;
    const int bm = blockIdx.y * 64, bn = blockIdx.x * 64;
    const int kb = blockIdx.z * KC;
    const int kend = (kb + KC < K) ? kb + KC : K;
    float* Pp = P + (size_t)blockIdx.z * M * N;

    float blk[4][4] = {};

    for (int k0 = kb; k0 < kend; k0 += 16) {
        {
            int row = tid >> 2, q = tid & 3;
            int gr = bm + row, gk = k0 + q * 4;
            float4 v = make_float4(0.f, 0.f, 0.f, 0.f);
            if (gr < M) {
                if (gk + 3 < kend) {
                    v = *(const float4*)(A + (size_t)gr * K + gk);
                } else {
                    float* vp = (float*)&v;
#pragma unroll
                    for (int e = 0; e < 4; ++e)
                        if (gk + e < kend) vp[e] = A[(size_t)gr * K + gk + e];
                }
            }
            float* vp = (float*)&v;
#pragma unroll
            for (int e = 0; e < 4; ++e) As[q * 4 + e][row] = vp[e];
        }
        {
            int kk = tid >> 4, c = (tid & 15) * 4;
            int gk = k0 + kk, gc = bn + c;
            float4 v = make_float4(0.f, 0.f, 0.f, 0.f);
            if (gk < kend) {
                if (gc + 3 < N) {
                    v = *(const float4*)(B + (size_t)gk * N + gc);
                } else {
                    float* vp = (float*)&v;
#pragma unroll
                    for (int e = 0; e < 4; ++e)
                        if (gc + e < N) vp[e] = B[(size_t)gk * N + gc + e];
                }
            }
            *(float4*)&Bs[kk][c] = v;
        }
        __syncthreads();
#pragma unroll
        for (int kk = 0; kk < 16; ++kk) {
            float a[4], b[4];
            *(float4*)&a[0] = *(const float4*)&As[kk][ty * 4];
            *(float4*)&b[0] = *(const float4*)&Bs[kk][tx * 4];
#pragma unroll
            for (int i = 0; i < 4; ++i)
#pragma unroll
                for (int j = 0; j < 4; ++j)
                    blk[i][j] = fmaf(a[i], b[j], blk[i][j]);   // strict asc. k
        }
        __syncthreads();
    }

#pragma unroll
    for (int i = 0; i < 4; ++i) {
        int r = bm + ty * 4 + i;
        if (r >= M) continue;
        float* Prow = Pp + (size_t)r * N;
        int c = bn + tx * 4;
        if (c + 3 < N) {
            float4 s; s.x = blk[i][0]; s.y = blk[i][1];
            s.z = blk[i][2]; s.w = blk[i][3];
            *(float4*)(Prow + c) = s;
        } else {
#pragma unroll
            for (int e = 0; e < 4; ++e)
                if (c + e < N) Prow[c + e] = blk[i][e];
        }
    }
}

// ordered panel combine: acc = P0; acc = fadd_rn(acc, P1); ... (frozen fold)
__global__ __launch_bounds__(256)
void combine3_k(const float* __restrict__ P, float* __restrict__ C, size_t nelem)
{
    const size_t i4 = (size_t)(blockIdx.x * 256 + threadIdx.x);
    const size_t stride = (size_t)gridDim.x * 256;
    const size_t n4 = nelem / 4;
    for (size_t i = i4; i < n4; i += stride) {
        float4 a = *(const float4*)(P + i * 4);
        float4 b = *(const float4*)(P + nelem + i * 4);
        float4 c = *(const float4*)(P + 2 * nelem + i * 4);
        float4 o;
        o.x = __fadd_rn(__fadd_rn(a.x, b.x), c.x);
        o.y = __fadd_rn(__fadd_rn(a.y, b.y), c.y);
        o.z = __fadd_rn(__fadd_rn(a.z, b.z), c.z);
        o.w = __fadd_rn(__fadd_rn(a.w, b.w), c.w);
        *(float4*)(C + i * 4) = o;
    }
}

// ---------------------------------------------------------------------------
__global__ __launch_bounds__(256)
void rownorm2_k(const float* __restrict__ X, float* __restrict__ wn)
{
    __shared__ float buf[400];
    __shared__ float leaf[4];
    const int row = blockIdx.x;
    const float* Xr = X + (size_t)row * 400;
    for (int i = threadIdx.x; i < 100; i += 256)
        *(float4*)&buf[i * 4] = *(const float4*)(Xr + i * 4);
    __syncthreads();
    if (threadIdx.x < 4) {
        const int off = (threadIdx.x >> 1) * 200 + ((threadIdx.x & 1) ? 96 : 0);
        const int len = (threadIdx.x & 1) ? 104 : 96;
        leaf[threadIdx.x] = np_pairwise<0>(buf + off, len);
    }
    __syncthreads();
    if (threadIdx.x == 0) {
        float s = __fadd_rn(__fadd_rn(leaf[0], leaf[1]),
                            __fadd_rn(leaf[2], leaf[3]));
        wn[row] = __fsqrt_rn(s);
    }
}

__global__ __launch_bounds__(256)
void rowabs2_k(const float* __restrict__ A, float* __restrict__ rs)
{
    __shared__ float buf[4000];
    __shared__ float leaf[8];
    const int row = blockIdx.x;
    const float* Ar = A + (size_t)row * 4000;
    for (int i = threadIdx.x; i < 1000; i += 256)
        *(float4*)&buf[i * 4] = *(const float4*)(Ar + i * 4);
    __syncthreads();
    if (threadIdx.x < 8) {
        const int off = (threadIdx.x >> 1) * 1000 + ((threadIdx.x & 1) ? 496 : 0);
        const int len = (threadIdx.x & 1) ? 504 : 496;
        leaf[threadIdx.x] = np_pairwise<1>(buf + off, len);
    }
    __syncthreads();
    if (threadIdx.x == 0) {
        float s = __fadd_rn(
            __fadd_rn(__fadd_rn(leaf[0], leaf[1]), __fadd_rn(leaf[2], leaf[3])),
            __fadd_rn(__fadd_rn(leaf[4], leaf[5]), __fadd_rn(leaf[6], leaf[7])));
        rs[row] = fmaxf(s, 1e-12f);
    }
}

// ---------------------------------------------------------------------------
// radix rank-select. state = {prefix, k_remaining}. Also zeroes cnt[].
// ---------------------------------------------------------------------------
__global__ void init_k(unsigned* __restrict__ state, const void* __restrict__ epn,
                       int* __restrict__ cnt)
{
    const int t = blockIdx.x * 256 + threadIdx.x;
    if (t < NN) cnt[t] = 0;
    if (t == 0) {
        int k = ((const int*)epn)[0];
        if (k <= 0 || k > 4000) {
            float f = ((const float*)epn)[0];
            if (f > 0.f && f <= 4000.f) k = (int)f;
            else {
                long long ll = ((const long long*)epn)[0];
                if (ll > 0 && ll <= 4000) k = (int)ll;
                else {
                    double dd = ((const double*)epn)[0];
                    k = (dd > 0.0 && dd <= 4000.0) ? (int)dd : 10;
                }
            }
        }
        state[0] = 0u;
        state[1] = (unsigned)(k * NN);
    }
}

// weighted triangle histogram (passes 2-4); per-block partials.
__global__ __launch_bounds__(256)
void hist_tri_k(const float* __restrict__ dist, unsigned* __restrict__ partial,
                const unsigned* __restrict__ state, int shift, int n)
{
    __shared__ unsigned lh[2048];
    for (int i = threadIdx.x; i < 2048; i += 256) lh[i] = 0;
    __syncthreads();
    const unsigned prefix = state[0];
    const int sub = threadIdx.x & 7;
    const int npair = (n + 1) / 2;
    for (int p = blockIdx.x; p < npair; p += HBLK) {
#pragma unroll
        for (int half = 0; half < 2; ++half) {
            const int i = half ? (n - 1 - p) : p;
            if (half && i == p) break;
            const float* row = dist + (size_t)i * n;
            for (int j = i + threadIdx.x; j < n; j += 256) {
                unsigned u = __float_as_uint(row[j]);
                unsigned key = (u & 0x80000000u) ? ~u : (u | 0x80000000u);
                bool ok = ((key >> (shift + 8)) == prefix);
                if (ok) atomicAdd(&lh[((((key >> shift) & 0xFFu)) << 3) | sub],
                                  (j == i) ? 1u : 2u);
            }
        }
    }
    __syncthreads();
    unsigned t = 0;
#pragma unroll
    for (int s = 0; s < 8; ++s) t += lh[(threadIdx.x << 3) | s];
    partial[blockIdx.x * 256 + threadIdx.x] = t;
}

// parallel partial reduction: block b = bin b; threads stride-sum partials.
__global__ __launch_bounds__(256)
void reduce_k(const unsigned* __restrict__ partial, int nparts,
              unsigned* __restrict__ hist256)
{
    const int bin = blockIdx.x;
    const int tid = threadIdx.x;
    unsigned s = 0;
    for (int i = tid; i < nparts; i += 256)
        s += partial[(size_t)i * 256 + bin];
    __shared__ unsigned sh[256];
    sh[tid] = s;
    __syncthreads();
    for (int off = 128; off > 0; off >>= 1) {
        if (tid < off) sh[tid] += sh[tid + off];
        __syncthreads();
    }
    if (tid == 0) hist256[bin] = sh[0];
}

// tiny 256-bin scan + radix descend
__global__ __launch_bounds__(256)
void scan256_k(const unsigned* __restrict__ hist256, unsigned* __restrict__ state,
               int shift, float* __restrict__ param)
{
    const int tid = threadIdx.x;
    unsigned h = hist256[tid];
    __shared__ unsigned sh[256];
    sh[tid] = h;
    __syncthreads();
    for (int off = 1; off < 256; off <<= 1) {
        unsigned v = (tid >= off) ? sh[tid - off] : 0;
        __syncthreads();
        sh[tid] += v;
        __syncthreads();
    }
    const unsigned incl = sh[tid], excl = incl - h;
    const unsigned krem = state[1];
    if (krem >= excl && krem < incl) {
        unsigned np = (state[0] << 8) | (unsigned)tid;
        state[0] = np;
        state[1] = krem - excl;
        if (shift == 0) {
            unsigned u = (np & 0x80000000u) ? (np ^ 0x80000000u) : ~np;
            *param = __uint_as_float(u);
        }
    }
}

// ---------------------------------------------------------------------------
__device__ inline float thr_f(float d, int i, int j, float p)
{
    float a = (d <= p && i != j) ? __fsub_rn(1.0f, d) : 0.0f;
    return (i == j) ? 1.0f : a;
}

// 64-aligned threshold upper tiles + mirror lower via LDS transpose;
// per-row nonzero counts via ballot (identical to count_k on stored values).
__global__ __launch_bounds__(256)
void symthresh_mirror_k(float* __restrict__ adj, const float* __restrict__ param,
                        int* __restrict__ cnt, int n)
{
    __shared__ float TB[64][65];
    const float p = *param;
    const int nt = (n + 63) >> 6;
    int bi = 0, rem = blockIdx.x;
    while (rem >= nt - bi) { rem -= nt - bi; ++bi; }
    const int bj = bi + rem;
    const int tid = threadIdx.x;
    const int lane = tid & 63;
    const int r0i = bi * 64, r0j = bj * 64;

#pragma unroll
    for (int it = 0; it < 16; ++it) {
        int idx = tid + it * 256;
        int q = idx >> 6, c = idx & 63;
        int gr = r0i + q, gc = r0j + c;
        bool inb = (gr < n && gc < n);
        float a = 0.f;
        if (inb) {
            a = thr_f(adj[(size_t)gr * n + gc], gr, gc, p);
            adj[(size_t)gr * n + gc] = a;
            TB[q][c] = a;
        }
        unsigned long long m = __ballot(inb && a != 0.0f);
        if (lane == 0 && gr < n) atomicAdd(&cnt[gr], (int)__popcll(m));
    }
    __syncthreads();
    if (bi != bj) {
#pragma unroll
        for (int it = 0; it < 16; ++it) {
            int idx = tid + it * 256;
            int q = idx >> 6, c = idx & 63;
            int gr = r0j + q, gc = r0i + c;
            bool inb = (gr < n && gc < n);
            float a = 0.f;
            if (inb) {
                a = TB[c][q];
                adj[(size_t)gr * n + gc] = a;
            }
            unsigned long long m = __ballot(inb && a != 0.0f);
            if (lane == 0 && gr < n) atomicAdd(&cnt[gr], (int)__popcll(m));
        }
    }
}

__global__ __launch_bounds__(256)
void norm_k(float* __restrict__ adj, const float* __restrict__ rs, int n)
{
    const int i = blockIdx.y;
    const int j = blockIdx.x * 256 + threadIdx.x;
    if (j >= n) return;
    const size_t idx = (size_t)i * n + j;
    adj[idx] = __fdiv_rn(adj[idx], rs[i]);
}

// ---------------------------------------------------------------------------
__global__ __launch_bounds__(256)
void count_k(const float* __restrict__ A, int* __restrict__ cnt, int n)
{
    const int gw = (blockIdx.x * blockDim.x + threadIdx.x) >> 6;
    if (gw >= n) return;
    const int lane = threadIdx.x & 63;
    int c = 0;
    for (int k0 = 0; k0 < n; k0 += 64) {
        int k = k0 + lane;
        bool nz = (k < n) && (A[(size_t)gw * n + k] != 0.0f);
        unsigned long long m = __ballot(nz);
        c += (int)__popcll(m);
    }
    if (lane == 0) cnt[gw] = c;
}

__global__ __launch_bounds__(1024)
void scanrows_k(const int* __restrict__ cnt, int* __restrict__ roff)
{
    const int t = threadIdx.x;
    int vals[4];
    int s0 = 0;
#pragma unroll
    for (int e = 0; e < 4; ++e) {
        int r = t * 4 + e;
        vals[e] = (r < NN) ? cnt[r] : 0;
        s0 += vals[e];
    }
    __shared__ int sh[1024];
    sh[t] = s0;
    __syncthreads();
    for (int off = 1; off < 1024; off <<= 1) {
        int v = (t >= off) ? sh[t - off] : 0;
        __syncthreads();
        sh[t] += v;
        __syncthreads();
    }
    int excl = sh[t] - s0;
#pragma unroll
    for (int e = 0; e < 4; ++e) {
        int r = t * 4 + e;
        if (r <= NN) roff[r] = excl;
        excl += vals[e];
    }
    if (t == 1023) roff[NN] = sh[1023];
}

template<bool DIV>
__global__ __launch_bounds__(256)
void fill_k(const float* __restrict__ A, const int* __restrict__ roff,
            const float* __restrict__ rs, int* __restrict__ ridx,
            float* __restrict__ rval, int n)
{
    const int gw = (blockIdx.x * blockDim.x + threadIdx.x) >> 6;
    if (gw >= n) return;
    const int lane = threadIdx.x & 63;
    const float r = DIV ? rs[gw] : 1.0f;
    int base = roff[gw];
    const unsigned long long ltmask = (lane == 63) ? ~0ULL >> 1
                                                   : ((1ULL << lane) - 1);
    for (int k0 = 0; k0 < n; k0 += 64) {
        int k = k0 + lane;
        float v = (k < n) ? A[(size_t)gw * n + k] : 0.f;
        bool nz = (v != 0.0f);
        unsigned long long m = __ballot(nz);
        if (nz) {
            int pos = base + (int)__popcll(m & ltmask);
            ridx[pos] = k;
            rval[pos] = DIV ? __fdiv_rn(v, r) : v;
        }
        base += (int)__popcll(m);
    }
}

// WN: also compute wn[r] = sqrt_rn(np_pairwise<0>(H row)) in the epilogue.
template<bool WN>
__global__ __launch_bounds__(256)
void spmm_k(const int* __restrict__ roff, const int* __restrict__ ridx,
            const float* __restrict__ rval, const float* __restrict__ T,
            const float* __restrict__ bias, float* __restrict__ H, int ncols,
            float* __restrict__ wn)
{
    __shared__ int ks[128];
    __shared__ float vs[128];
    __shared__ float buf[512];
    __shared__ float leaf[4];
    const int r = blockIdx.x;
    const int tid = threadIdx.x;
    const int c0 = tid, c1 = tid + 256;
    const bool ok0 = c0 < ncols, ok1 = c1 < ncols;
    float acc0 = 0.f, blk0 = 0.f, acc1 = 0.f, blk1 = 0.f;
    int nb = KC;
    const int s = roff[r], e = roff[r + 1];
    for (int base = s; base < e; base += 128) {
        const int m = (e - base < 128) ? (e - base) : 128;
        __syncthreads();
        if (tid < m) { ks[tid] = ridx[base + tid]; vs[tid] = rval[base + tid]; }
        __syncthreads();
        for (int t = 0; t < m; ++t) {
            const int k = ks[t];
            const float v = vs[t];
            while (k >= nb) {
                acc0 = __fadd_rn(acc0, blk0); blk0 = 0.f;
                acc1 = __fadd_rn(acc1, blk1); blk1 = 0.f;
                nb += KC;
            }
            const float* Tr = T + (size_t)k * ncols;
            if (ok0) blk0 = fmaf(v, Tr[c0], blk0);
            if (ok1) blk1 = fmaf(v, Tr[c1], blk1);
        }
    }
    acc0 = __fadd_rn(acc0, blk0);
    acc1 = __fadd_rn(acc1, blk1);
    float h0 = 0.f, h1 = 0.f;
    if (ok0) {
        float s0 = __fadd_rn(acc0, bias[c0]);
        h0 = (s0 >= 0.f) ? s0 : __fmul_rn(LEAKY, s0);
        H[(size_t)r * ncols + c0] = h0;
    }
    if (ok1) {
        float s1 = __fadd_rn(acc1, bias[c1]);
        h1 = (s1 >= 0.f) ? s1 : __fmul_rn(LEAKY, s1);
        H[(size_t)r * ncols + c1] = h1;
    }
    if (WN) {
        if (ok0) buf[c0] = h0;
        if (ok1) buf[c1] = h1;
        __syncthreads();
        if (tid < 4) {
            const int off = (tid >> 1) * 200 + ((tid & 1) ? 96 : 0);
            const int len = (tid & 1) ? 104 : 96;
            leaf[tid] = np_pairwise<0>(buf + off, len);
        }
        __syncthreads();
        if (tid == 0) {
            float s2 = __fadd_rn(__fadd_rn(leaf[0], leaf[1]),
                                 __fadd_rn(leaf[2], leaf[3]));
            wn[r] = __fsqrt_rn(s2);
        }
    }
}

// ---------------------------------------------------------------------------
template<int EPI, bool TRANSB, bool FIRST, bool LAST>
__global__ __launch_bounds__(256, 4)
void gemm_pass_k(const float* __restrict__ A, const float* __restrict__ B,
                 float* __restrict__ C, int M, int N, int K, int kb, int kend,
                 const float* __restrict__ bias, const float* __restrict__ wn)
{
    __shared__ float As[16][132];
    __shared__ float Bs[16][132];
    const int tid = threadIdx.x;
    const int tx = tid & 15, ty = tid >> 4;
    const int bm = blockIdx.y * 128, bn = blockIdx.x * 128;

    float blk[8][8] = {};

    for (int k0 = kb; k0 < kend; k0 += 16) {
#pragma unroll
        for (int it = 0; it < 2; ++it) {
            int idx = tid + it * 256;
            int row = idx >> 2, q = idx & 3;
            int gr = bm + row, gk = k0 + q * 4;
            float4 v = make_float4(0.f, 0.f, 0.f, 0.f);
            if (gr < M) {
                if (gk + 3 < kend) {
                    v = *(const float4*)(A + (size_t)gr * K + gk);
                } else {
                    float* vp = (float*)&v;
#pragma unroll
                    for (int e = 0; e < 4; ++e)
                        if (gk + e < kend) vp[e] = A[(size_t)gr * K + gk + e];
                }
            }
            float* vp = (float*)&v;
#pragma unroll
            for (int e = 0; e < 4; ++e) As[q * 4 + e][row] = vp[e];
        }
        if (!TRANSB) {
#pragma unroll
            for (int it = 0; it < 2; ++it) {
                int idx = tid + it * 256;
                int kk = idx >> 5, cq = idx & 31;
                int gk = k0 + kk, c = cq * 4, gc = bn + c;
                float4 v = make_float4(0.f, 0.f, 0.f, 0.f);
                if (gk < kend) {
                    if (gc + 3 < N) {
                        v = *(const float4*)(B + (size_t)gk * N + gc);
                    } else {
                        float* vp = (float*)&v;
#pragma unroll
                        for (int e = 0; e < 4; ++e)
                            if (gc + e < N) vp[e] = B[(size_t)gk * N + gc + e];
                    }
                }
                *(float4*)&Bs[kk][c] = v;
            }
        } else {
#pragma unroll
            for (int it = 0; it < 2; ++it) {
                int idx = tid + it * 256;
                int row = idx >> 2, q = idx & 3;
                int gc = bn + row, gk = k0 + q * 4;
                float4 v = make_float4(0.f, 0.f, 0.f, 0.f);
                if (gc < N) {
                    if (gk + 3 < kend) {
                        v = *(const float4*)(B + (size_t)gc * K + gk);
                    } else {
                        float* vp = (float*)&v;
#pragma unroll
                        for (int e = 0; e < 4; ++e)
                            if (gk + e < kend) vp[e] = B[(size_t)gc * K + gk + e];
                    }
                }
                float* vp = (float*)&v;
#pragma unroll
                for (int e = 0; e < 4; ++e) Bs[q * 4 + e][row] = vp[e];
            }
        }
        __syncthreads();
#pragma unroll
        for (int kk = 0; kk < 16; ++kk) {
            float a[8], b[8];
            *(float4*)&a[0] = *(const float4*)&As[kk][ty * 4];
            *(float4*)&a[4] = *(const float4*)&As[kk][ty * 4 + 64];
            *(float4*)&b[0] = *(const float4*)&Bs[kk][tx * 4];
            *(float4*)&b[4] = *(const float4*)&Bs[kk][tx * 4 + 64];
#pragma unroll
            for (int i = 0; i < 8; ++i)
#pragma unroll
                for (int j = 0; j < 8; ++j)
                    blk[i][j] = fmaf(a[i], b[j], blk[i][j]);
        }
        __syncthreads();
    }

#pragma unroll
    for (int i = 0; i < 8; ++i) {
        int r = bm + ty * 4 + (i & 3) + (i >> 2) * 64;
        if (r >= M) continue;
        float* Crow = C + (size_t)r * N;
#pragma unroll
        for (int h = 0; h < 2; ++h) {
            int c = bn + tx * 4 + h * 64;
            float v[4];
#pragma unroll
            for (int e = 0; e < 4; ++e) v[e] = blk[i][h * 4 + e];
            if (c + 3 < N) {
                if (!FIRST) {
                    float4 o = *(const float4*)(Crow + c);
                    v[0] = __fadd_rn(o.x, v[0]); v[1] = __fadd_rn(o.y, v[1]);
                    v[2] = __fadd_rn(o.z, v[2]); v[3] = __fadd_rn(o.w, v[3]);
                }
                if (LAST) {
#pragma unroll
                    for (int e = 0; e < 4; ++e)
                        v[e] = epi_apply<EPI>(v[e], r, c + e, bias, wn);
                }
                float4 s; s.x = v[0]; s.y = v[1]; s.z = v[2]; s.w = v[3];
                *(float4*)(Crow + c) = s;
            } else {
#pragma unroll
                for (int e = 0; e < 4; ++e) {
                    if (c + e >= N) continue;
                    float vv = v[e];
                    if (!FIRST) vv = __fadd_rn(Crow[c + e], vv);
                    if (LAST) vv = epi_apply<EPI>(vv, r, c + e, bias, wn);
                    Crow[c + e] = vv;
                }
            }
        }
    }
}

template<int EPI, bool TRANSB>
static void run_gemm(const float* A, const float* B, float* C,
                     int M, int N, int K, const float* bias, const float* wn,
                     hipStream_t stream)
{
    const int nb = (K + KC - 1) / KC;
    const dim3 grid((N + 127) / 128, (M + 127) / 128);
    for (int p = 0; p < nb; ++p) {
        const int kb = p * KC;
        const int kend = (kb + KC < K) ? kb + KC : K;
        const bool first = (p == 0), last = (p == nb - 1);
        if (first && last)
            gemm_pass_k<EPI, TRANSB, true, true><<<grid, 256, 0, stream>>>(
                A, B, C, M, N, K, kb, kend, bias, wn);
        else if (first)
            gemm_pass_k<EPI, TRANSB, true, false><<<grid, 256, 0, stream>>>(
                A, B, C, M, N, K, kb, kend, bias, wn);
        else if (last)
            gemm_pass_k<EPI, TRANSB, false, true><<<grid, 256, 0, stream>>>(
                A, B, C, M, N, K, kb, kend, bias, wn);
        else
            gemm_pass_k<EPI, TRANSB, false, false><<<grid, 256, 0, stream>>>(
                A, B, C, M, N, K, kb, kend, bias, wn);
    }
}

extern "C" void kernel_launch(void* const* d_in, const int* in_sizes, int n_in,
                              void* d_out, int out_size, void* d_ws, size_t ws_size,
                              hipStream_t stream)
{
    const void*  epn  = d_in[0];
    const float* x    = (const float*)d_in[1];
    const float* adj0 = (const float*)d_in[2];
    const float* w1   = (const float*)d_in[3];
    const float* b1   = (const float*)d_in[4];
    const float* w2   = (const float*)d_in[5];
    const float* b2   = (const float*)d_in[6];
    const float* w3   = (const float*)d_in[7];
    const float* b3   = (const float*)d_in[8];
    float* out = (float*)d_out;

    char* ws = (char*)d_ws;
    float*    dist    = (float*)   ws;                     // 64,000,000
    float*    Tbuf    = (float*)  (ws + 64000000);         //  6,400,000
    float*    H1      = (float*)  (ws + 70400000);         //  6,400,000
    float*    H2      = (float*)  (ws + 76800000);         //  6,400,000
    float*    wn      = (float*)  (ws + 83200000);         //     16,000
    float*    rs      = (float*)  (ws + 83216000);         //     16,000
    unsigned* state   = (unsigned*)(ws + 83232000);        //          8
    float*    param   = (float*)  (ws + 83232008);         //          4
    unsigned* hist256 = (unsigned*)(ws + 83232064);        //      1,024
    unsigned* partial = (unsigned*)(ws + 83233088);        //  2,064,384 (2016x256)
    int*      cnt     = (int*)    (ws + 85297472);         //     16,000
    int*      roff    = (int*)    (ws + 85313472);         //     16,008
    int*      ridx    = (int*)    (ws + 85329480);         // 16,000,000
    float*    rval    = (float*)  (ws + 101329480);        // 16,000,000
    float*    panels  = (float*)  (ws + 85329480);         // alias: 3x6.4MB,
                                  // live only before layer-1 CSR build
    const bool use_csr = (ws_size >= 117329480ULL + 64);

    const int gsN = (NN + 63) / 64;   // 63
    const int nt64 = (NN + 63) / 64;
    const int nsym64 = nt64 * (nt64 + 1) / 2;   // == NPART1 == 2016

    auto genadj = [&](const float* H, bool have_wn) {
        if (!have_wn)
            rownorm2_k<<<NN, 256, 0, stream>>>(H, wn);
        gemm_tri64_k<<<nsym64, 256, 0, stream>>>(H, dist, partial, NN, 400, wn);
        init_k<<<16, 256, 0, stream>>>(state, epn, cnt);
        reduce_k<<<256, 256, 0, stream>>>(partial, NPART1, hist256);
        scan256_k<<<1, 256, 0, stream>>>(hist256, state, 24, param);
        for (int p = 1; p < 4; ++p) {
            const int shift = 24 - 8 * p;
            hist_tri_k<<<HBLK, 256, 0, stream>>>(dist, partial, state, shift, NN);
            reduce_k<<<256, 256, 0, stream>>>(partial, HBLK, hist256);
            scan256_k<<<1, 256, 0, stream>>>(hist256, state, shift, param);
        }
        symthresh_mirror_k<<<nsym64, 256, 0, stream>>>(dist, param, cnt, NN);
        rowabs2_k<<<NN, 256, 0, stream>>>(dist, rs);
    };

    auto aggregate_pre = [&](const float* Aadj, const float* Tm,
                             const float* bias, float* Hout, int ncols,
                             bool want_wn) {
        if (use_csr) {
            count_k<<<(NN + 3) / 4, 256, 0, stream>>>(Aadj, cnt, NN);
            scanrows_k<<<1, 1024, 0, stream>>>(cnt, roff);
            fill_k<false><<<(NN + 3) / 4, 256, 0, stream>>>(Aadj, roff, nullptr,
                                                            ridx, rval, NN);
            if (want_wn)
                spmm_k<true><<<NN, 256, 0, stream>>>(roff, ridx, rval, Tm, bias,
                                                     Hout, ncols, wn);
            else
                spmm_k<false><<<NN, 256, 0, stream>>>(roff, ridx, rval, Tm, bias,
                                                      Hout, ncols, nullptr);
        } else {
            run_gemm<1, false>(Aadj, Tm, Hout, NN, ncols, NN, bias,
                               nullptr, stream);
        }
    };

    auto aggregate_rs = [&](float* Aadj, const float* Tm,
                            const float* bias, float* Hout, int ncols,
                            bool want_wn) {
        if (use_csr) {
            scanrows_k<<<1, 1024, 0, stream>>>(cnt, roff);
            fill_k<true><<<(NN + 3) / 4, 256, 0, stream>>>(Aadj, roff, rs,
                                                           ridx, rval, NN);
            if (want_wn)
                spmm_k<true><<<NN, 256, 0, stream>>>(roff, ridx, rval, Tm, bias,
                                                     Hout, ncols, wn);
            else
                spmm_k<false><<<NN, 256, 0, stream>>>(roff, ridx, rval, Tm, bias,
                                                      Hout, ncols, nullptr);
        } else {
            norm_k<<<dim3((NN + 255) / 256, NN), 256, 0, stream>>>(Aadj, rs, NN);
            run_gemm<1, false>(Aadj, Tm, Hout, NN, ncols, NN, bias,
                               nullptr, stream);
        }
    };

    // ---- Layer 1: Tbuf = x@w1 (split-K over 3 KC panels, ordered combine)
    if (use_csr) {
        gemm_panel_k<<<dim3((400 + 63) / 64, gsN, 3), 256, 0, stream>>>(
            x, w1, panels, NN, 400, 1000);
        combine3_k<<<1024, 256, 0, stream>>>(panels, Tbuf, (size_t)NN * 400);
    } else {
        gemm_s_k<0><<<dim3((400 + 63) / 64, gsN), 256, 0, stream>>>(
            x, w1, Tbuf, NN, 400, 1000, nullptr);
    }
    aggregate_pre(adj0, Tbuf, b1, H1, 400, use_csr);

    // ---- gen_adj(H1) + Layer 2 (+wn of H2)
    genadj(H1, use_csr);
    gemm_s_k<0><<<dim3((400 + 63) / 64, gsN), 256, 0, stream>>>(
        H1, w2, Tbuf, NN, 400, 400, nullptr);
    aggregate_rs(dist, Tbuf, b2, H2, 400, use_csr);

    // ---- gen_adj(H2) + Layer 3
    genadj(H2, use_csr);
    gemm_s_k<0><<<dim3((200 + 63) / 64, gsN), 256, 0, stream>>>(
        H2, w3, Tbuf, NN, 200, 400, nullptr);
    aggregate_rs(dist, Tbuf, b3, out, 200, false);
}